// Round 5
// baseline (75221.844 us; speedup 1.0000x reference)
//
#include <hip/hip_runtime.h>
#include <cstdint>
#include <cstddef>

// ============================================================================
// VoiceCloningGenerator — dense frag-major transport round (compile-fixed).
// h-state and all scan weights stored in MFMA-fragment order [kb][m|g][64][8]
// so every load is a wave-contiguous 1KB read (100% line efficiency at the
// coherence point). Weights stream from L2 (cached, frag-major). 16 cols/WG.
// Uniform 2-deep pipelined inner loop; load-poll barrier.
// ============================================================================

#define DEVI __device__ __forceinline__

typedef short bf16x8 __attribute__((ext_vector_type(8)));
typedef float f32x4 __attribute__((ext_vector_type(4)));
typedef unsigned short u16x4 __attribute__((ext_vector_type(4)));

constexpr int B_ = 64, L_ = 512, T_ = 1000, E_ = 256, H_ = 512, M_ = 80, S_ = 128, Hd_ = 256;

DEVI unsigned short f2bs(float f) {
  unsigned u = __builtin_bit_cast(unsigned, f);
  unsigned r = u + 0x7fffu + ((u >> 16) & 1u);
  return (unsigned short)(r >> 16);
}
DEVI float b2f(unsigned short s) { return __builtin_bit_cast(float, (unsigned)s << 16); }
DEVI void split2(float v, unsigned short& hi, unsigned short& lo) {
  hi = f2bs(v);
  lo = f2bs(v - b2f(hi));
}
DEVI float sigm(float x) { x = fminf(fmaxf(x, -30.f), 30.f); return 1.f / (1.f + __expf(-x)); }
DEVI float tanh_(float x) { x = fminf(fmaxf(x, -15.f), 15.f); float e = __expf(2.f * x); return (e - 1.f) / (e + 1.f); }

DEVI f32x4 mfma16(bf16x8 a, bf16x8 b, f32x4 c) {
  return __builtin_amdgcn_mfma_f32_16x16x32_bf16(a, b, c, 0, 0, 0);
}

DEVI int kb_base(int wv) { return (wv < 3) ? wv * 9 : 27; }

// --- memory ops ------------------------------------------------------------
DEVI void ldg16(bf16x8& r, const unsigned short* p) {  // cached (L1/L2)
  asm volatile("global_load_dwordx4 %0, %1, off" : "=v"(r) : "v"(p));
}
DEVI void ldc16(bf16x8& r, const unsigned short* p) {  // coherence point (IC)
  asm volatile("global_load_dwordx4 %0, %1, off sc0 sc1" : "=v"(r) : "v"(p));
}
DEVI void st8c(unsigned short* p, u16x4 v) {
  asm volatile("global_store_dwordx2 %0, %1, off sc0 sc1" :: "v"(p), "v"(v));
}
DEVI int pollld(const int* p) {
  int v;
  asm volatile("global_load_dword %0, %1, off sc0 sc1\ns_waitcnt vmcnt(0)"
               : "=v"(v) : "v"(p) : "memory");
  return v;
}
#define WAITV(N) do { asm volatile("s_waitcnt vmcnt(" #N ")" ::: "memory"); \
                      __builtin_amdgcn_sched_barrier(0); } while (0)
#define VM_DRAIN() WAITV(0)

// --- grid barrier: hierarchical arrive (relaxed agent RMW) + load-poll -----
struct Bar { int sub[8][64]; int master[64]; int release[64]; };

DEVI void grid_bar(Bar* bb, int nwg, int step) {
  __syncthreads();
  if (threadIdx.x == 0) {
    const int per = nwg >> 3;
    int old = __hip_atomic_fetch_add(&bb->sub[blockIdx.x & 7][0], 1,
                                     __ATOMIC_RELAXED, __HIP_MEMORY_SCOPE_AGENT);
    if (old == per * (step + 1) - 1) {
      int om = __hip_atomic_fetch_add(&bb->master[0], 1,
                                      __ATOMIC_RELAXED, __HIP_MEMORY_SCOPE_AGENT);
      if (om == 8 * (step + 1) - 1)
        __hip_atomic_fetch_add(&bb->release[0], 1,
                               __ATOMIC_RELAXED, __HIP_MEMORY_SCOPE_AGENT);
    }
    while (pollld(&bb->release[0]) < step + 1) __builtin_amdgcn_s_sleep(1);
  }
  __syncthreads();
}

// --- 2-deep pipelined load/MFMA loop. Batch = 16 loads (8 A + 8 B). --------
template <int N, class FI, class FM>
DEVI void pipe_run(FI issue, FM domf) {
  bf16x8 S0[16], S1[16];
  issue(0, S0);
  if constexpr (N > 1) issue(1, S1);
#pragma unroll
  for (int j = 0; j < N; ++j) {
    if (j + 1 < N) { WAITV(16); } else { WAITV(0); }
    if (j & 1) { domf(S1); if (j + 2 < N) issue(j + 2, S1); }
    else       { domf(S0); if (j + 2 < N) issue(j + 2, S0); }
  }
}

// ---------------------------------------------------------------------------
// Prep: emb hi/lo, mel rows hi/lo (row-major), mel-MLP weights bf16.
// ---------------------------------------------------------------------------
__global__ void k_prep(const float* __restrict__ embed, const float* __restrict__ tmel,
                       const float* __restrict__ mw1, const float* __restrict__ mw2,
                       unsigned short* emb_h, unsigned short* emb_l,
                       unsigned short* mel_h, unsigned short* mel_l,
                       unsigned short* w1_bf, unsigned short* w2_bf) {
  const long long stride = (long long)gridDim.x * blockDim.x;
  const long long i0 = (long long)blockIdx.x * blockDim.x + threadIdx.x;
  for (long long i = i0; i < 256 * 256; i += stride) {
    unsigned short h, l; split2(embed[i], h, l);
    emb_h[i] = h; emb_l[i] = l;
  }
  for (long long i = i0; i < (long long)T_ * B_ * 96; i += stride) {
    int c = (int)(i % 96);
    long long tb = i / 96;
    int b = (int)(tb % B_);
    int t = (int)(tb / B_);
    float v = 0.f;
    if (t > 0 && c < 80) v = tmel[((long long)b * T_ + (t - 1)) * M_ + c];
    unsigned short h, l; split2(v, h, l);
    mel_h[i] = h; mel_l[i] = l;
  }
  for (long long i = i0; i < 512 * 512; i += stride) w1_bf[i] = f2bs(mw1[i]);
  for (long long i = i0; i < 80 * 512; i += stride) w2_bf[i] = f2bs(mw2[i]);
}

// ---------------------------------------------------------------------------
// Weight prep: frag-major hi/lo for encoder (2 dir x 16 cg) and decoder
// (L0: 32 cg x 35 kb, L1: 32 cg x 32 kb).  Frag element (kb,g,ln,j):
// R = g*Hrows + cg*16 + (ln&15), k = kb*32 + (ln>>4)*8 + j.
// ---------------------------------------------------------------------------
__global__ void k_wprep(
    const float* __restrict__ WihF, const float* __restrict__ WhhF,
    const float* __restrict__ WihB, const float* __restrict__ WhhB,
    const float* __restrict__ Wih0, const float* __restrict__ Whh0,
    const float* __restrict__ Wih1, const float* __restrict__ Whh1,
    unsigned short* wEh, unsigned short* wEl,
    unsigned short* wD0h, unsigned short* wD0l,
    unsigned short* wD1h, unsigned short* wD1l) {
  const long long stride = (long long)gridDim.x * blockDim.x;
  const long long i0 = (long long)blockIdx.x * blockDim.x + threadIdx.x;
  // encoder: [dir][cg16][kb16][g4][64][8]
  for (long long i = i0; i < 2097152; i += stride) {
    int j = i & 7, ln = (i >> 3) & 63, g = (i >> 9) & 3, kb = (i >> 11) & 15;
    int cg = (i >> 15) & 15, dir = (int)(i >> 19);
    const float* Wih = dir ? WihB : WihF;
    const float* Whh = dir ? WhhB : WhhF;
    int R = g * Hd_ + cg * 16 + (ln & 15);
    int k = kb * 32 + ((ln >> 4) & 3) * 8 + j;
    float v = (k < E_) ? Wih[(size_t)R * E_ + k] : Whh[(size_t)R * Hd_ + (k - E_)];
    unsigned short a, b; split2(v, a, b);
    wEh[i] = a; wEl[i] = b;
  }
  // dec L0: [cg32][kb35][g4][64][8]; K: [0,96) mel (80 real), [96,608) query, [608,1120) h0
  for (long long i = i0; i < 2293760; i += stride) {
    int j = i & 7, ln = (i >> 3) & 63, g = (i >> 9) & 3;
    int t3 = (int)(i >> 11);
    int kb = t3 % 35, cg = t3 / 35;
    int R = g * H_ + cg * 16 + (ln & 15);
    int k = kb * 32 + ((ln >> 4) & 3) * 8 + j;
    float v;
    if (k < 96)       v = (k < 80) ? Wih0[(size_t)R * 592 + k] : 0.f;
    else if (k < 608) v = Wih0[(size_t)R * 592 + (k - 16)];
    else              v = Whh0[(size_t)R * H_ + (k - 608)];
    unsigned short a, b; split2(v, a, b);
    wD0h[i] = a; wD0l[i] = b;
  }
  // dec L1: [cg32][kb32][g4][64][8]; K: [0,512) h0, [512,1024) h1
  for (long long i = i0; i < 2097152; i += stride) {
    int j = i & 7, ln = (i >> 3) & 63, g = (i >> 9) & 3, kb = (i >> 11) & 31;
    int cg = (int)(i >> 16);
    int R = g * H_ + cg * 16 + (ln & 15);
    int k = kb * 32 + ((ln >> 4) & 3) * 8 + j;
    float v = (k < 512) ? Wih1[(size_t)R * H_ + k] : Whh1[(size_t)R * H_ + (k - 512)];
    unsigned short a, b; split2(v, a, b);
    wD1h[i] = a; wD1l[i] = b;
  }
}

// ---------------------------------------------------------------------------
__global__ void __launch_bounds__(512) k_sp(const float* __restrict__ spk,
                                            const float* __restrict__ w1, const float* __restrict__ b1,
                                            const float* __restrict__ w2, const float* __restrict__ b2,
                                            float* sp) {
  __shared__ float t1[512];
  const int b = blockIdx.x, j = threadIdx.x;
  float a = b1[j];
  const float* sr = spk + b * S_;
  for (int k = 0; k < S_; ++k) a += sr[k] * w1[j * S_ + k];
  t1[j] = fmaxf(a, 0.f);
  __syncthreads();
  float a2 = b2[j];
  for (int k = 0; k < H_; ++k) a2 += t1[k] * w2[j * H_ + k];
  sp[b * H_ + j] = a2;
}

// ---------------------------------------------------------------------------
// Encoder: 32 WGs = 2 dir x 16 cg (16 cols each). K=512: kb 0-7 embed (cached
// gather), kb 8-15 h (frag, IC). Weights frag-major from L2. hencf layout:
// [par][dir][kb8][m4][64][8].
// ---------------------------------------------------------------------------
__global__ void __launch_bounds__(256, 1) k_enc(
    const int* __restrict__ text,
    const float* __restrict__ bF, const float* __restrict__ bB,
    const unsigned short* __restrict__ emb_h, const unsigned short* __restrict__ emb_l,
    const unsigned short* __restrict__ wEh, const unsigned short* __restrict__ wEl,
    const float* __restrict__ sp,
    unsigned short* hencfh, unsigned short* hencfl,
    unsigned short* ench, unsigned short* encl, Bar* bar) {
  __shared__ float G[4096];
  const int wg = blockIdx.x;
  const int dir = wg >> 4;
  const int cg = wg & 15;
  const int jhb = cg * 16;
  const int tid = threadIdx.x;
  const int wv = tid >> 6, ln = tid & 63, lg = ln >> 4, lr = ln & 15;
  const int kb0 = wv * 4;

  const unsigned short* wbh = wEh + ((size_t)(dir * 16 + cg)) * 32768;
  const unsigned short* wbl = wEl + ((size_t)(dir * 16 + cg)) * 32768;
  const float* bb = dir ? bB : bF;

  const int eb = tid >> 2, ej0 = (tid & 3) * 4;
  float c4[4] = {0.f, 0.f, 0.f, 0.f};
  float spv[4], bv[4][4];
#pragma unroll
  for (int q = 0; q < 4; ++q) spv[q] = sp[eb * H_ + dir * Hd_ + jhb + ej0 + q];
#pragma unroll
  for (int g = 0; g < 4; ++g)
#pragma unroll
    for (int q = 0; q < 4; ++q) bv[g][q] = bb[g * Hd_ + jhb + ej0 + q];

  // elementwise write mapping (frag target)
  const int jh = jhb + ej0;
  const int lkb_w = jh >> 5;
  const int lane_w = ((jh >> 3) & 3) * 16 + (eb & 15);
  const int m_w = eb >> 4;
  const size_t fro = ((size_t)(lkb_w * 4 + m_w) * 64 + lane_w) * 8 + (jh & 7);

  for (int t = 0; t < L_; ++t) {
    const int tpos = dir ? (L_ - 1 - t) : t;
    const unsigned short* hsh = hencfh + ((size_t)((t & 1) * 2 + dir)) * 16384;
    const unsigned short* hsl = hencfl + ((size_t)((t & 1) * 2 + dir)) * 16384;

    for (int i = tid; i < 1024; i += 256) ((f32x4*)G)[i] = (f32x4){0.f, 0.f, 0.f, 0.f};

    int tix[4];
#pragma unroll
    for (int m = 0; m < 4; ++m) tix[m] = text[(16 * m + lr) * L_ + tpos];

    f32x4 acc[4][4];
#pragma unroll
    for (int g = 0; g < 4; ++g)
#pragma unroll
      for (int m = 0; m < 4; ++m) acc[g][m] = (f32x4){0.f, 0.f, 0.f, 0.f};

    auto issue = [&](int j, bf16x8 (&S)[16]) {
      const int kb = kb0 + j;
      if (kb < 8) {
        const int k0 = kb * 32 + lg * 8;
#pragma unroll
        for (int m = 0; m < 4; ++m) {
          ldg16(S[m],     emb_h + (size_t)tix[m] * E_ + k0);
          ldg16(S[4 + m], emb_l + (size_t)tix[m] * E_ + k0);
        }
      } else {
        const unsigned short* ah = hsh + ((size_t)((kb - 8) * 4) * 64 + ln) * 8;
        const unsigned short* al = hsl + ((size_t)((kb - 8) * 4) * 64 + ln) * 8;
#pragma unroll
        for (int m = 0; m < 4; ++m) { ldc16(S[m], ah + m * 512); ldc16(S[4 + m], al + m * 512); }
      }
      const unsigned short* bh = wbh + ((size_t)(kb * 4) * 64 + ln) * 8;
      const unsigned short* bl = wbl + ((size_t)(kb * 4) * 64 + ln) * 8;
#pragma unroll
      for (int g = 0; g < 4; ++g) { ldg16(S[8 + g], bh + g * 512); ldg16(S[12 + g], bl + g * 512); }
    };
    auto domf = [&](bf16x8 (&S)[16]) {
#pragma unroll
      for (int g = 0; g < 4; ++g)
#pragma unroll
        for (int m = 0; m < 4; ++m) {
          acc[g][m] = mfma16(S[m],     S[8 + g],  acc[g][m]);
          acc[g][m] = mfma16(S[4 + m], S[8 + g],  acc[g][m]);
          acc[g][m] = mfma16(S[m],     S[12 + g], acc[g][m]);
        }
    };
    pipe_run<4>(issue, domf);

    __syncthreads();
#pragma unroll
    for (int g = 0; g < 4; ++g)
#pragma unroll
      for (int m = 0; m < 4; ++m)
#pragma unroll
        for (int r = 0; r < 4; ++r)
          atomicAdd(&G[(g * 64 + 16 * m + 4 * lg + r) * 16 + lr], acc[g][m][r]);
    __syncthreads();

    {
      unsigned short* hdh = hencfh + ((size_t)(((t + 1) & 1) * 2 + dir)) * 16384;
      unsigned short* hdl = hencfl + ((size_t)(((t + 1) & 1) * 2 + dir)) * 16384;
      float gvv[4][4];
#pragma unroll
      for (int g = 0; g < 4; ++g) {
        f32x4 x = *(const f32x4*)&G[(g * 64 + eb) * 16 + ej0];
#pragma unroll
        for (int q = 0; q < 4; ++q) gvv[g][q] = x[q] + bv[g][q];
      }
      u16x4 hvh, hvl, ovh, ovl;
#pragma unroll
      for (int q = 0; q < 4; ++q) {
        float cn = sigm(gvv[1][q]) * c4[q] + sigm(gvv[0][q]) * tanh_(gvv[2][q]);
        c4[q] = cn;
        float h = sigm(gvv[3][q]) * tanh_(cn);
        unsigned short a, b; split2(h, a, b);
        hvh[q] = a; hvl[q] = b;
        split2(h + spv[q], a, b);
        ovh[q] = a; ovl[q] = b;
      }
      st8c(hdh + fro, hvh);
      st8c(hdl + fro, hvl);
      *(u16x4*)(ench + ((size_t)eb * L_ + tpos) * H_ + dir * Hd_ + jhb + ej0) = ovh;
      *(u16x4*)(encl + ((size_t)eb * L_ + tpos) * H_ + dir * Hd_ + jhb + ej0) = ovl;
    }
    VM_DRAIN();
    grid_bar(bar, 32, t);
  }
}

// ---------------------------------------------------------------------------
// Decoder: 64 WGs = 2 layer x 32 cg (16 cols each), pipelined by one tick.
// h frag layout: [par][kb16][m4][64][8].
// ---------------------------------------------------------------------------
__global__ void __launch_bounds__(256, 1) k_dec(
    const float* __restrict__ b0, const float* __restrict__ b1,
    const unsigned short* __restrict__ wD0h, const unsigned short* __restrict__ wD0l,
    const unsigned short* __restrict__ wD1h, const unsigned short* __restrict__ wD1l,
    const unsigned short* __restrict__ ench, const unsigned short* __restrict__ encl,
    const unsigned short* __restrict__ melh, const unsigned short* __restrict__ mell,
    unsigned short* h0fh, unsigned short* h0fl,
    unsigned short* h1fh, unsigned short* h1fl,
    unsigned short* h2_full, Bar* bar) {
  __shared__ float G[4096];
  const int wg = blockIdx.x;
  const int layer = wg >> 5;
  const int cg = wg & 31;
  const int jcb = cg * 16;
  const int tid = threadIdx.x, wv = tid >> 6, ln = tid & 63, lg = ln >> 4, lr = ln & 15;

  const unsigned short* wbh = layer ? (wD1h + (size_t)cg * 65536) : (wD0h + (size_t)cg * 71680);
  const unsigned short* wbl = layer ? (wD1l + (size_t)cg * 65536) : (wD0l + (size_t)cg * 71680);
  const float* bglob = layer ? b1 : b0;

  const int eb = tid & 63, c0 = (tid >> 6) * 4;
  float c4[4] = {0.f, 0.f, 0.f, 0.f};
  float bv[4][4];
#pragma unroll
  for (int g = 0; g < 4; ++g)
#pragma unroll
    for (int q = 0; q < 4; ++q) bv[g][q] = bglob[g * H_ + jcb + c0 + q];

  const int j0 = jcb + c0;
  const size_t fro = ((size_t)((j0 >> 5) * 4 + (eb >> 4)) * 64 + (((j0 >> 3) & 3) * 16 + (eb & 15))) * 8 + (j0 & 7);

  for (int tau = 0; tau <= T_; ++tau) {
    const bool active = (layer == 0) ? (tau < T_) : (tau >= 1);
    if (active) {
      const int t = (layer == 0) ? tau : tau - 1;
      for (int i = tid; i < 1024; i += 256) ((f32x4*)G)[i] = (f32x4){0.f, 0.f, 0.f, 0.f};

      f32x4 acc[4][4];
#pragma unroll
      for (int g = 0; g < 4; ++g)
#pragma unroll
        for (int m = 0; m < 4; ++m) acc[g][m] = (f32x4){0.f, 0.f, 0.f, 0.f};

      auto domf = [&](bf16x8 (&S)[16]) {
#pragma unroll
        for (int g = 0; g < 4; ++g)
#pragma unroll
          for (int m = 0; m < 4; ++m) {
            acc[g][m] = mfma16(S[m],     S[8 + g],  acc[g][m]);
            acc[g][m] = mfma16(S[4 + m], S[8 + g],  acc[g][m]);
            acc[g][m] = mfma16(S[m],     S[12 + g], acc[g][m]);
          }
      };

      if (layer == 0) {
        const int tq = t & (L_ - 1);
        const unsigned short* p0h = h0fh + (size_t)((tau + 1) & 1) * 32768;
        const unsigned short* p0l = h0fl + (size_t)((tau + 1) & 1) * 32768;
        auto issue = [&](int j, bf16x8 (&S)[16]) {
          const int kb = kb_base(wv) + j;
          const int k0 = kb * 32 + lg * 8;
          if (kb < 3) {
#pragma unroll
            for (int m = 0; m < 4; ++m) {
              ldg16(S[m],     melh + ((size_t)t * B_ + 16 * m + lr) * 96 + k0);
              ldg16(S[4 + m], mell + ((size_t)t * B_ + 16 * m + lr) * 96 + k0);
            }
          } else if (kb < 19) {
            const int k = k0 - 96;
#pragma unroll
            for (int m = 0; m < 4; ++m) {
              ldg16(S[m],     ench + ((size_t)(16 * m + lr) * L_ + tq) * H_ + k);
              ldg16(S[4 + m], encl + ((size_t)(16 * m + lr) * L_ + tq) * H_ + k);
            }
          } else {
            const unsigned short* ah = p0h + ((size_t)((kb - 19) * 4) * 64 + ln) * 8;
            const unsigned short* al = p0l + ((size_t)((kb - 19) * 4) * 64 + ln) * 8;
#pragma unroll
            for (int m = 0; m < 4; ++m) { ldc16(S[m], ah + m * 512); ldc16(S[4 + m], al + m * 512); }
          }
          const unsigned short* bh = wbh + ((size_t)(kb * 4) * 64 + ln) * 8;
          const unsigned short* bl = wbl + ((size_t)(kb * 4) * 64 + ln) * 8;
#pragma unroll
          for (int g = 0; g < 4; ++g) { ldg16(S[8 + g], bh + g * 512); ldg16(S[12 + g], bl + g * 512); }
        };
        if (wv < 3) pipe_run<9>(issue, domf);
        else        pipe_run<8>(issue, domf);
      } else {
        const unsigned short* q0h = h0fh + (size_t)((tau + 1) & 1) * 32768;
        const unsigned short* q0l = h0fl + (size_t)((tau + 1) & 1) * 32768;
        const unsigned short* q1h = h1fh + (size_t)(tau & 1) * 32768;
        const unsigned short* q1l = h1fl + (size_t)(tau & 1) * 32768;
        const int kb0 = wv * 8;
        auto issue = [&](int j, bf16x8 (&S)[16]) {
          const int kb = kb0 + j;
          const unsigned short *ah, *al;
          if (kb < 16) {
            ah = q0h + ((size_t)(kb * 4) * 64 + ln) * 8;
            al = q0l + ((size_t)(kb * 4) * 64 + ln) * 8;
          } else {
            ah = q1h + ((size_t)((kb - 16) * 4) * 64 + ln) * 8;
            al = q1l + ((size_t)((kb - 16) * 4) * 64 + ln) * 8;
          }
#pragma unroll
          for (int m = 0; m < 4; ++m) { ldc16(S[m], ah + m * 512); ldc16(S[4 + m], al + m * 512); }
          const unsigned short* bh = wbh + ((size_t)(kb * 4) * 64 + ln) * 8;
          const unsigned short* bl = wbl + ((size_t)(kb * 4) * 64 + ln) * 8;
#pragma unroll
          for (int g = 0; g < 4; ++g) { ldg16(S[8 + g], bh + g * 512); ldg16(S[12 + g], bl + g * 512); }
        };
        pipe_run<8>(issue, domf);
      }

      __syncthreads();
#pragma unroll
      for (int g = 0; g < 4; ++g)
#pragma unroll
        for (int m = 0; m < 4; ++m)
#pragma unroll
          for (int r = 0; r < 4; ++r)
            atomicAdd(&G[(g * 64 + 16 * m + 4 * lg + r) * 16 + lr], acc[g][m][r]);
      __syncthreads();

      {
        unsigned short* dh = layer ? (h1fh + (size_t)((tau + 1) & 1) * 32768)
                                   : (h0fh + (size_t)(tau & 1) * 32768);
        unsigned short* dl = layer ? (h1fl + (size_t)((tau + 1) & 1) * 32768)
                                   : (h0fl + (size_t)(tau & 1) * 32768);
        float gvv[4][4];
#pragma unroll
        for (int g = 0; g < 4; ++g) {
          f32x4 x = *(const f32x4*)&G[(g * 64 + eb) * 16 + c0];
#pragma unroll
          for (int q = 0; q < 4; ++q) gvv[g][q] = x[q] + bv[g][q];
        }
        u16x4 hv, lv;
#pragma unroll
        for (int q = 0; q < 4; ++q) {
          float cn = sigm(gvv[1][q]) * c4[q] + sigm(gvv[0][q]) * tanh_(gvv[2][q]);
          c4[q] = cn;
          float h = sigm(gvv[3][q]) * tanh_(cn);
          unsigned short a, b; split2(h, a, b);
          hv[q] = a; lv[q] = b;
        }
        st8c(dh + fro, hv);
        st8c(dl + fro, lv);
        if (layer) *(u16x4*)(h2_full + ((size_t)t * B_ + eb) * H_ + j0) = hv;
      }
      VM_DRAIN();
    }
    grid_bar(bar, 64, tau);
  }
}

// ---------------------------------------------------------------------------
constexpr int MLP_LDS = 64 * 1024;

__global__ void __launch_bounds__(256) k_mlp(
    const unsigned short* __restrict__ h2_full,
    const unsigned short* __restrict__ w1_bf, const unsigned short* __restrict__ w2_bf,
    const float* __restrict__ mb1, const float* __restrict__ mb2,
    const float* __restrict__ stW, const float* __restrict__ stb, float* out) {
  extern __shared__ char lds[];
  const int t = blockIdx.x;
  const int tid = threadIdx.x, wv = tid >> 6, ln = tid & 63, lg = ln >> 4, lr = ln & 15;
  const unsigned short* A = h2_full + (size_t)t * B_ * H_;

  for (int half = 0; half < 2; ++half) {
    const int nb = wv * 8 + half * 4;
    f32x4 acc[4][4];
#pragma unroll
    for (int nn = 0; nn < 4; ++nn) {
      float bvv = mb1[(nb + nn) * 16 + lr];
#pragma unroll
      for (int m = 0; m < 4; ++m) acc[m][nn] = (f32x4){bvv, bvv, bvv, bvv};
    }
    for (int kb = 0; kb < 16; ++kb) {
      int k0 = kb * 32 + lg * 8;
      bf16x8 afr[4], bfr[4];
#pragma unroll
      for (int m = 0; m < 4; ++m) afr[m] = *(const bf16x8*)(A + (size_t)(16 * m + lr) * H_ + k0);
#pragma unroll
      for (int nn = 0; nn < 4; ++nn) bfr[nn] = *(const bf16x8*)(w1_bf + (size_t)((nb + nn) * 16 + lr) * H_ + k0);
#pragma unroll
      for (int m = 0; m < 4; ++m)
#pragma unroll
        for (int nn = 0; nn < 4; ++nn) acc[m][nn] = mfma16(afr[m], bfr[nn], acc[m][nn]);
    }
#pragma unroll
    for (int m = 0; m < 4; ++m)
#pragma unroll
      for (int nn = 0; nn < 4; ++nn)
#pragma unroll
        for (int r = 0; r < 4; ++r) {
          int row = 16 * m + 4 * lg + r, col = (nb + nn) * 16 + lr;
          *(unsigned short*)(lds + row * 1024 + ((col * 2) ^ ((row & 7) << 4))) =
              f2bs(fmaxf(acc[m][nn][r], 0.f));
        }
  }
  __syncthreads();

  {
    f32x4 acc2[5];
#pragma unroll
    for (int n = 0; n < 5; ++n) {
      float bvv = mb2[n * 16 + lr];
      acc2[n] = (f32x4){bvv, bvv, bvv, bvv};
    }
    for (int kb = 0; kb < 16; ++kb) {
      int k0 = kb * 32 + lg * 8;
      int row = 16 * wv + lr;
      bf16x8 afr = *(bf16x8*)(lds + row * 1024 + ((k0 * 2) ^ ((row & 7) << 4)));
#pragma unroll
      for (int n = 0; n < 5; ++n) {
        bf16x8 bfr = *(const bf16x8*)(w2_bf + (size_t)(n * 16 + lr) * H_ + k0);
        acc2[n] = mfma16(afr, bfr, acc2[n]);
      }
    }
#pragma unroll
    for (int n = 0; n < 5; ++n)
#pragma unroll
      for (int r = 0; r < 4; ++r) {
        int b = 16 * wv + 4 * lg + r;
        out[((size_t)b * T_ + t) * M_ + n * 16 + lr] = acc2[n][r];
      }
  }

  if (tid < 64) {
    int b = tid;
    float s = stb[0];
    const unsigned short* hp = A + (size_t)b * H_;
    for (int k = 0; k < H_; ++k) s += b2f(hp[k]) * stW[k];
    out[(size_t)B_ * T_ * M_ + (size_t)b * T_ + t] = s;
  }
}

// ---------------------------------------------------------------------------
extern "C" void kernel_launch(void* const* d_in, const int* in_sizes, int n_in,
                              void* d_out, int out_size, void* d_ws, size_t ws_size,
                              hipStream_t stream) {
  (void)in_sizes; (void)n_in; (void)out_size; (void)ws_size;
  const int* text = (const int*)d_in[0];
  const float* spk = (const float*)d_in[1];
  const float* tmel = (const float*)d_in[2];
  const float* embed = (const float*)d_in[3];
  const float* eWihF = (const float*)d_in[4];
  const float* eWhhF = (const float*)d_in[5];
  const float* ebF = (const float*)d_in[6];
  const float* eWihB = (const float*)d_in[7];
  const float* eWhhB = (const float*)d_in[8];
  const float* ebB = (const float*)d_in[9];
  const float* spW1 = (const float*)d_in[10];
  const float* spb1 = (const float*)d_in[11];
  const float* spW2 = (const float*)d_in[12];
  const float* spb2 = (const float*)d_in[13];
  const float* dWih0 = (const float*)d_in[14];
  const float* dWhh0 = (const float*)d_in[15];
  const float* db0 = (const float*)d_in[16];
  const float* dWih1 = (const float*)d_in[17];
  const float* dWhh1 = (const float*)d_in[18];
  const float* db1 = (const float*)d_in[19];
  const float* mW1 = (const float*)d_in[20];
  const float* mb1 = (const float*)d_in[21];
  const float* mW2 = (const float*)d_in[22];
  const float* mb2 = (const float*)d_in[23];
  const float* stW = (const float*)d_in[24];
  const float* stb = (const float*)d_in[25];
  float* out = (float*)d_out;

  char* base = (char*)d_ws;
  size_t off = 0;
  auto carve = [&](size_t bytes) -> void* {
    void* p = base + off;
    off += (bytes + 255) & ~(size_t)255;
    return p;
  };
  // --- state region (zeroed each call) ---
  Bar* barE = (Bar*)carve(sizeof(Bar));
  Bar* barD = (Bar*)carve(sizeof(Bar));
  unsigned short* h0fh = (unsigned short*)carve(2 * 32768 * 2);   // [par][16][4][64][8]
  unsigned short* h0fl = (unsigned short*)carve(2 * 32768 * 2);
  unsigned short* h1fh = (unsigned short*)carve(2 * 32768 * 2);
  unsigned short* h1fl = (unsigned short*)carve(2 * 32768 * 2);
  unsigned short* hencfh = (unsigned short*)carve(4 * 16384 * 2); // [par][dir][8][4][64][8]
  unsigned short* hencfl = (unsigned short*)carve(4 * 16384 * 2);
  const size_t state_bytes = off;
  // --- write-before-read buffers ---
  float* sp = (float*)carve((size_t)B_ * H_ * 4);
  unsigned short* emb_h = (unsigned short*)carve((size_t)256 * 256 * 2);
  unsigned short* emb_l = (unsigned short*)carve((size_t)256 * 256 * 2);
  unsigned short* mel_h = (unsigned short*)carve((size_t)T_ * B_ * 96 * 2);
  unsigned short* mel_l = (unsigned short*)carve((size_t)T_ * B_ * 96 * 2);
  unsigned short* w1_bf = (unsigned short*)carve((size_t)512 * 512 * 2);
  unsigned short* w2_bf = (unsigned short*)carve((size_t)80 * 512 * 2);
  unsigned short* ench = (unsigned short*)carve((size_t)B_ * L_ * H_ * 2);
  unsigned short* encl = (unsigned short*)carve((size_t)B_ * L_ * H_ * 2);
  unsigned short* h2_full = (unsigned short*)carve((size_t)T_ * B_ * H_ * 2);
  unsigned short* wEh = (unsigned short*)carve((size_t)2097152 * 2);
  unsigned short* wEl = (unsigned short*)carve((size_t)2097152 * 2);
  unsigned short* wD0h = (unsigned short*)carve((size_t)2293760 * 2);
  unsigned short* wD0l = (unsigned short*)carve((size_t)2293760 * 2);
  unsigned short* wD1h = (unsigned short*)carve((size_t)2097152 * 2);
  unsigned short* wD1l = (unsigned short*)carve((size_t)2097152 * 2);

  hipMemsetAsync(d_ws, 0, state_bytes, stream);

  hipFuncSetAttribute((const void*)k_mlp, hipFuncAttributeMaxDynamicSharedMemorySize, MLP_LDS);

  k_prep<<<2048, 256, 0, stream>>>(embed, tmel, mW1, mW2, emb_h, emb_l, mel_h, mel_l, w1_bf, w2_bf);
  k_wprep<<<2048, 256, 0, stream>>>(eWihF, eWhhF, eWihB, eWhhB, dWih0, dWhh0, dWih1, dWhh1,
                                    wEh, wEl, wD0h, wD0l, wD1h, wD1l);
  k_sp<<<64, 512, 0, stream>>>(spk, spW1, spb1, spW2, spb2, sp);
  k_enc<<<32, 256, 0, stream>>>(text, ebF, ebB, emb_h, emb_l, wEh, wEl, sp,
                                hencfh, hencfl, ench, encl, barE);
  k_dec<<<64, 256, 0, stream>>>(db0, db1, wD0h, wD0l, wD1h, wD1l, ench, encl,
                                mel_h, mel_l, h0fh, h0fl, h1fh, h1fl, h2_full, barD);
  k_mlp<<<1000, 256, MLP_LDS, stream>>>(h2_full, w1_bf, w2_bf, mb1, mb2, stW, stb, out);
}

// Round 6
// 34659.814 us; speedup vs baseline: 2.1703x; 2.1703x over previous
//
#include <hip/hip_runtime.h>
#include <cstdint>
#include <cstddef>

// ============================================================================
// VoiceCloningGenerator — R3 structure + frag-major dense h transport.
// Weights hi/lo in LDS (loaded once). h rings stored in MFMA fragment order
// [kb][m][64][8] so every cross-XCD h read is a wave-contiguous 1KB request.
// ============================================================================

#define DEVI __device__ __forceinline__

typedef short bf16x8 __attribute__((ext_vector_type(8)));
typedef float f32x4 __attribute__((ext_vector_type(4)));
typedef unsigned short u16x4 __attribute__((ext_vector_type(4)));

constexpr int B_ = 64, L_ = 512, T_ = 1000, E_ = 256, H_ = 512, M_ = 80, S_ = 128, Hd_ = 256;

DEVI unsigned short f2bs(float f) {
  unsigned u = __builtin_bit_cast(unsigned, f);
  unsigned r = u + 0x7fffu + ((u >> 16) & 1u);
  return (unsigned short)(r >> 16);
}
DEVI float b2f(unsigned short s) { return __builtin_bit_cast(float, (unsigned)s << 16); }
DEVI void split2(float v, unsigned short& hi, unsigned short& lo) {
  hi = f2bs(v);
  lo = f2bs(v - b2f(hi));
}
DEVI float sigm(float x) { x = fminf(fmaxf(x, -30.f), 30.f); return 1.f / (1.f + __expf(-x)); }
DEVI float tanh_(float x) { x = fminf(fmaxf(x, -15.f), 15.f); float e = __expf(2.f * x); return (e - 1.f) / (e + 1.f); }

DEVI f32x4 mfma16(bf16x8 a, bf16x8 b, f32x4 c) {
  return __builtin_amdgcn_mfma_f32_16x16x32_bf16(a, b, c, 0, 0, 0);
}

// --- coherence-point (cross-XCD) memory ops --------------------------------
DEVI void ldc16(bf16x8& r, const unsigned short* p) {
  asm volatile("global_load_dwordx4 %0, %1, off sc0 sc1" : "=v"(r) : "v"(p));
}
DEVI void st4c(unsigned short* p, unsigned v) {
  asm volatile("global_store_dword %0, %1, off sc0 sc1" :: "v"(p), "v"(v));
}
DEVI void st8c(unsigned short* p, u16x4 v) {
  asm volatile("global_store_dwordx2 %0, %1, off sc0 sc1" :: "v"(p), "v"(v));
}
DEVI int pollld(const int* p) {
  int v;
  asm volatile("global_load_dword %0, %1, off sc0 sc1\ns_waitcnt vmcnt(0)"
               : "=v"(v) : "v"(p) : "memory");
  return v;
}
#define VM_DRAIN() do { asm volatile("s_waitcnt vmcnt(0)" ::: "memory"); \
                        __builtin_amdgcn_sched_barrier(0); } while (0)
#define VM_WAIT8_OR_0(LAST) do { \
    if (LAST) asm volatile("s_waitcnt vmcnt(0)" ::: "memory"); \
    else      asm volatile("s_waitcnt vmcnt(8)" ::: "memory"); \
    __builtin_amdgcn_sched_barrier(0); } while (0)

// --- grid barrier: hierarchical arrive (relaxed agent RMW) + load-poll -----
struct Bar { int sub[8][64]; int master[64]; int release[64]; };

DEVI void grid_bar(Bar* bb, int nwg, int step) {
  __syncthreads();
  if (threadIdx.x == 0) {
    const int per = nwg >> 3;
    int old = __hip_atomic_fetch_add(&bb->sub[blockIdx.x & 7][0], 1,
                                     __ATOMIC_RELAXED, __HIP_MEMORY_SCOPE_AGENT);
    if (old == per * (step + 1) - 1) {
      int om = __hip_atomic_fetch_add(&bb->master[0], 1,
                                      __ATOMIC_RELAXED, __HIP_MEMORY_SCOPE_AGENT);
      if (om == 8 * (step + 1) - 1)
        __hip_atomic_fetch_add(&bb->release[0], 1,
                               __ATOMIC_RELAXED, __HIP_MEMORY_SCOPE_AGENT);
    }
    while (pollld(&bb->release[0]) < step + 1) __builtin_amdgcn_s_sleep(1);
  }
  __syncthreads();
}

// ---------------------------------------------------------------------------
__global__ void k_prep(const float* __restrict__ embed, const float* __restrict__ tmel,
                       const float* __restrict__ mw1, const float* __restrict__ mw2,
                       unsigned short* emb_h, unsigned short* emb_l,
                       unsigned short* mel_h, unsigned short* mel_l,
                       unsigned short* w1_bf, unsigned short* w2_bf) {
  const long long stride = (long long)gridDim.x * blockDim.x;
  const long long i0 = (long long)blockIdx.x * blockDim.x + threadIdx.x;
  for (long long i = i0; i < 256 * 256; i += stride) {
    unsigned short h, l; split2(embed[i], h, l);
    emb_h[i] = h; emb_l[i] = l;
  }
  for (long long i = i0; i < (long long)T_ * B_ * 96; i += stride) {
    int c = (int)(i % 96);
    long long tb = i / 96;
    int b = (int)(tb % B_);
    int t = (int)(tb / B_);
    float v = 0.f;
    if (t > 0 && c < 80) v = tmel[((long long)b * T_ + (t - 1)) * M_ + c];
    unsigned short h, l; split2(v, h, l);
    mel_h[i] = h; mel_l[i] = l;
  }
  for (long long i = i0; i < 512 * 512; i += stride) w1_bf[i] = f2bs(mw1[i]);
  for (long long i = i0; i < 80 * 512; i += stride) w2_bf[i] = f2bs(mw2[i]);
}

// ---------------------------------------------------------------------------
__global__ void __launch_bounds__(512) k_sp(const float* __restrict__ spk,
                                            const float* __restrict__ w1, const float* __restrict__ b1,
                                            const float* __restrict__ w2, const float* __restrict__ b2,
                                            float* sp) {
  __shared__ float t1[512];
  const int b = blockIdx.x, j = threadIdx.x;
  float a = b1[j];
  const float* sr = spk + b * S_;
  for (int k = 0; k < S_; ++k) a += sr[k] * w1[j * S_ + k];
  t1[j] = fmaxf(a, 0.f);
  __syncthreads();
  float a2 = b2[j];
  for (int k = 0; k < H_; ++k) a2 += t1[k] * w2[j * H_ + k];
  sp[b * H_ + j] = a2;
}

// ---------------------------------------------------------------------------
// Encoder: 2 dirs x 16 WGs x 16 cols. Weights hi/lo in LDS (frag-ordered).
// henc frag ring: [par*2+dir][kb8][m4][64][8] (16384 elems per block).
// ---------------------------------------------------------------------------
constexpr int ENC_LDS = 2 * 16 * 4 * 64 * 16 + 4 * 64 * 16 * 4 + 256;  // 147712

__global__ void __launch_bounds__(256) k_enc(
    const int* __restrict__ text,
    const float* __restrict__ WihF, const float* __restrict__ WhhF, const float* __restrict__ bF,
    const float* __restrict__ WihB, const float* __restrict__ WhhB, const float* __restrict__ bB,
    const unsigned short* __restrict__ emb_h, const unsigned short* __restrict__ emb_l,
    const float* __restrict__ sp,
    unsigned short* hencfh, unsigned short* hencfl,
    unsigned short* ench, unsigned short* encl, Bar* bar) {
  extern __shared__ char lds[];
  unsigned short* Wh = (unsigned short*)lds;
  unsigned short* Wl = Wh + 16 * 4 * 64 * 8;
  float* G = (float*)(lds + 2 * 16 * 4 * 64 * 16);
  float* bias = G + 4 * 64 * 16;

  const int wg = blockIdx.x;
  const int dir = wg >> 4;
  const int jhb = (wg & 15) * 16;
  const int tid = threadIdx.x;
  const int wv = tid >> 6, ln = tid & 63, lg = ln >> 4, lr = ln & 15;

  const float* Wih = dir ? WihB : WihF;
  const float* Whh = dir ? WhhB : WhhF;
  const float* bb = dir ? bB : bF;

  for (int s = tid; s < 16 * 4 * 64; s += 256) {
    int kb = s >> 8, g = (s >> 6) & 3, l = s & 63;
    int R = g * Hd_ + jhb + (l & 15);
    int k0 = kb * 32 + (l >> 4) * 8;
    const float* src = (k0 < E_) ? (Wih + (size_t)R * E_ + k0) : (Whh + (size_t)R * Hd_ + (k0 - E_));
    bf16x8 vh, vl;
#pragma unroll
    for (int j = 0; j < 8; ++j) {
      unsigned short a, b; split2(src[j], a, b);
      vh[j] = (short)a; vl[j] = (short)b;
    }
    *(bf16x8*)(Wh + (size_t)s * 8) = vh;
    *(bf16x8*)(Wl + (size_t)s * 8) = vl;
  }
  if (tid < 64) bias[tid] = bb[(tid >> 4) * Hd_ + jhb + (tid & 15)];

  const int eb = tid >> 2, ej0 = (tid & 3) * 4;
  float c4[4] = {0.f, 0.f, 0.f, 0.f};
  float spv[4];
#pragma unroll
  for (int q = 0; q < 4; ++q) spv[q] = sp[eb * H_ + dir * Hd_ + jhb + ej0 + q];

  // frag-target write offset for this thread's 4 columns (jh..jh+3 contiguous)
  const int jh = jhb + ej0;
  const size_t fro = ((size_t)((jh >> 5) * 4 + (eb >> 4)) * 64 +
                      (((jh >> 3) & 3) * 16 + (eb & 15))) * 8 + (jh & 7);

  __syncthreads();

  for (int t = 0; t < L_; ++t) {
    const int tpos = dir ? (L_ - 1 - t) : t;
    const unsigned short* hsh = hencfh + ((size_t)((t & 1) * 2 + dir)) * 16384;
    const unsigned short* hsl = hencfl + ((size_t)((t & 1) * 2 + dir)) * 16384;
    unsigned short* hdh = hencfh + ((size_t)(((t + 1) & 1) * 2 + dir)) * 16384;
    unsigned short* hdl = hencfl + ((size_t)(((t + 1) & 1) * 2 + dir)) * 16384;

    for (int i = tid; i < 4096; i += 256) G[i] = bias[((i >> 10) << 4) + (i & 15)];

    int tix[4];
#pragma unroll
    for (int m = 0; m < 4; ++m) tix[m] = text[(16 * m + lr) * L_ + tpos];

    f32x4 acc[4][4];
#pragma unroll
    for (int g = 0; g < 4; ++g)
#pragma unroll
      for (int m = 0; m < 4; ++m) acc[g][m] = (f32x4){0.f, 0.f, 0.f, 0.f};

    auto MFE = [&](int kb, bf16x8 (&ah)[4], bf16x8 (&al)[4]) {
#pragma unroll
      for (int g = 0; g < 4; ++g) {
        bf16x8 bh = *(bf16x8*)(Wh + ((size_t)(kb * 4 + g) * 64 + ln) * 8);
        bf16x8 bl = *(bf16x8*)(Wl + ((size_t)(kb * 4 + g) * 64 + ln) * 8);
#pragma unroll
        for (int m = 0; m < 4; ++m) {
          acc[g][m] = mfma16(ah[m], bh, acc[g][m]);
          acc[g][m] = mfma16(al[m], bh, acc[g][m]);
          acc[g][m] = mfma16(ah[m], bl, acc[g][m]);
        }
      }
    };

    // phase A: embed kbs (cached gather loads)
    for (int kb = wv; kb < 8; kb += 4) {
      int k0 = kb * 32 + lg * 8;
      bf16x8 ah[4], al[4];
#pragma unroll
      for (int m = 0; m < 4; ++m) {
        ah[m] = *(const bf16x8*)(emb_h + (size_t)tix[m] * E_ + k0);
        al[m] = *(const bf16x8*)(emb_l + (size_t)tix[m] * E_ + k0);
      }
      MFE(kb, ah, al);
    }
    // phase B: h kbs via frag-major IC loads (wave-contiguous 1KB each)
    {
      auto issueE = [&](int kb, bf16x8 (&ah)[4], bf16x8 (&al)[4]) {
        const unsigned short* ph = hsh + ((size_t)((kb - 8) * 4) * 64 + ln) * 8;
        const unsigned short* pl = hsl + ((size_t)((kb - 8) * 4) * 64 + ln) * 8;
#pragma unroll
        for (int m = 0; m < 4; ++m) { ldc16(ah[m], ph + m * 512); ldc16(al[m], pl + m * 512); }
      };
      bf16x8 A0h[4], A0l[4], A1h[4], A1l[4];
      issueE(8 + wv, A0h, A0l);
      issueE(12 + wv, A1h, A1l);
      VM_WAIT8_OR_0(false);
      MFE(8 + wv, A0h, A0l);
      VM_WAIT8_OR_0(true);
      MFE(12 + wv, A1h, A1l);
    }

    __syncthreads();
#pragma unroll
    for (int g = 0; g < 4; ++g)
#pragma unroll
      for (int m = 0; m < 4; ++m)
#pragma unroll
        for (int r = 0; r < 4; ++r)
          atomicAdd(&G[(g * 64 + 16 * m + 4 * lg + r) * 16 + lr], acc[g][m][r]);
    __syncthreads();

    {
      u16x4 hvh, hvl, ovh, ovl;
#pragma unroll
      for (int q = 0; q < 4; ++q) {
        int jj = ej0 + q;
        float gi = G[(0 * 64 + eb) * 16 + jj];
        float gf = G[(1 * 64 + eb) * 16 + jj];
        float gg = G[(2 * 64 + eb) * 16 + jj];
        float go = G[(3 * 64 + eb) * 16 + jj];
        float cn = sigm(gf) * c4[q] + sigm(gi) * tanh_(gg);
        c4[q] = cn;
        float h = sigm(go) * tanh_(cn);
        unsigned short a, b; split2(h, a, b);
        hvh[q] = a; hvl[q] = b;
        float o = h + spv[q];
        split2(o, a, b);
        ovh[q] = a; ovl[q] = b;
      }
      st8c(hdh + fro, hvh);
      st8c(hdl + fro, hvl);
      *(u16x4*)(ench + ((size_t)eb * L_ + tpos) * H_ + dir * Hd_ + jhb + ej0) = ovh;
      *(u16x4*)(encl + ((size_t)eb * L_ + tpos) * H_ + dir * Hd_ + jhb + ej0) = ovl;
    }
    VM_DRAIN();
    grid_bar(bar, 32, t);
  }
}

// ---------------------------------------------------------------------------
// Decoder: 128 WGs (64/layer, 8 cols each), pipelined by one tick.
// h frag rings: [par][kb16][m4][64][8] (32768 elems per parity).
// ---------------------------------------------------------------------------
constexpr int DEC_LDS = 2 * 35 * 2 * 64 * 16 + 4 * 64 * 8 * 4 + 128;  // 151680

__global__ void __launch_bounds__(256) k_dec(
    const float* __restrict__ Wih0, const float* __restrict__ Whh0, const float* __restrict__ b0,
    const float* __restrict__ Wih1, const float* __restrict__ Whh1, const float* __restrict__ b1,
    const unsigned short* __restrict__ ench, const unsigned short* __restrict__ encl,
    const unsigned short* __restrict__ melh, const unsigned short* __restrict__ mell,
    unsigned short* h0fh, unsigned short* h0fl,
    unsigned short* h1fh, unsigned short* h1fl,
    unsigned short* h2_full, Bar* bar) {
  extern __shared__ char lds[];
  const int wg = blockIdx.x;
  const int layer = wg >> 6;
  const int jcb = (wg & 63) * 8;
  const int tid = threadIdx.x, wv = tid >> 6, ln = tid & 63, lg = ln >> 4, lr = ln & 15;
  const int NKB = layer ? 32 : 35;
  unsigned short* Wh = (unsigned short*)lds;
  unsigned short* Wl = Wh + (size_t)NKB * 2 * 64 * 8;
  float* G = (float*)(lds + (size_t)2 * NKB * 2 * 64 * 16);
  float* bias = G + 4 * 64 * 8;

  if (layer == 0) {
    for (int s = tid; s < 35 * 2 * 64; s += 256) {
      int kb = s >> 7, st = (s >> 6) & 1, l = s & 63;
      int n = l & 15;
      int R = (2 * st + (n >> 3)) * H_ + jcb + (n & 7);
      int k0 = kb * 32 + (l >> 4) * 8;
      bf16x8 vh, vl;
      if (k0 < 96) {
#pragma unroll
        for (int j = 0; j < 8; ++j) {
          int c = k0 + j;
          float v = (c < 80) ? Wih0[(size_t)R * 592 + c] : 0.f;
          unsigned short a, b; split2(v, a, b);
          vh[j] = (short)a; vl[j] = (short)b;
        }
      } else if (k0 < 608) {
        const float* src = Wih0 + (size_t)R * 592 + (k0 - 16);
#pragma unroll
        for (int j = 0; j < 8; ++j) {
          unsigned short a, b; split2(src[j], a, b);
          vh[j] = (short)a; vl[j] = (short)b;
        }
      } else {
        const float* src = Whh0 + (size_t)R * H_ + (k0 - 608);
#pragma unroll
        for (int j = 0; j < 8; ++j) {
          unsigned short a, b; split2(src[j], a, b);
          vh[j] = (short)a; vl[j] = (short)b;
        }
      }
      *(bf16x8*)(Wh + (size_t)s * 8) = vh;
      *(bf16x8*)(Wl + (size_t)s * 8) = vl;
    }
    if (tid < 32) bias[tid] = b0[(tid >> 3) * H_ + jcb + (tid & 7)];
  } else {
    for (int s = tid; s < 32 * 2 * 64; s += 256) {
      int kb = s >> 7, st = (s >> 6) & 1, l = s & 63;
      int n = l & 15;
      int R = (2 * st + (n >> 3)) * H_ + jcb + (n & 7);
      int k0 = kb * 32 + (l >> 4) * 8;
      const float* src = (k0 < 512) ? (Wih1 + (size_t)R * H_ + k0) : (Whh1 + (size_t)R * H_ + (k0 - 512));
      bf16x8 vh, vl;
#pragma unroll
      for (int j = 0; j < 8; ++j) {
        unsigned short a, b; split2(src[j], a, b);
        vh[j] = (short)a; vl[j] = (short)b;
      }
      *(bf16x8*)(Wh + (size_t)s * 8) = vh;
      *(bf16x8*)(Wl + (size_t)s * 8) = vl;
    }
    if (tid < 32) bias[tid] = b1[(tid >> 3) * H_ + jcb + (tid & 7)];
  }

  const int ebd = tid & 63, cc0 = (tid >> 6) * 2;
  float c2[2] = {0.f, 0.f};
  // frag-target write offset for this thread's 2 columns (j0w, j0w+1)
  const int j0w = jcb + cc0;
  const size_t frw = ((size_t)((j0w >> 5) * 4 + (ebd >> 4)) * 64 +
                      (((j0w >> 3) & 3) * 16 + (ebd & 15))) * 8 + (j0w & 7);
  __syncthreads();

  for (int tau = 0; tau <= T_; ++tau) {
    const bool active = (layer == 0) ? (tau < T_) : (tau >= 1);
    if (active) {
      const int t = (layer == 0) ? tau : tau - 1;
      for (int i = tid; i < 2048; i += 256) G[i] = bias[((i >> 9) << 3) + (i & 7)];

      f32x4 acc[2][4];
#pragma unroll
      for (int st = 0; st < 2; ++st)
#pragma unroll
        for (int m = 0; m < 4; ++m) acc[st][m] = (f32x4){0.f, 0.f, 0.f, 0.f};

      auto MF = [&](int kb, bf16x8 (&ah)[4], bf16x8 (&al)[4]) {
#pragma unroll
        for (int st = 0; st < 2; ++st) {
          bf16x8 bh = *(bf16x8*)(Wh + ((size_t)(kb * 2 + st) * 64 + ln) * 8);
          bf16x8 bl = *(bf16x8*)(Wl + ((size_t)(kb * 2 + st) * 64 + ln) * 8);
#pragma unroll
          for (int m = 0; m < 4; ++m) {
            acc[st][m] = mfma16(ah[m], bh, acc[st][m]);
            acc[st][m] = mfma16(al[m], bh, acc[st][m]);
            acc[st][m] = mfma16(ah[m], bl, acc[st][m]);
          }
        }
      };

      if (layer == 0) {
        const int tq = t & (L_ - 1);
        const unsigned short* p0h = h0fh + (size_t)((tau + 1) & 1) * 32768;
        const unsigned short* p0l = h0fl + (size_t)((tau + 1) & 1) * 32768;
        // phase A: mel + query (cached)
        for (int kb = wv; kb < 19; kb += 4) {
          int k0 = kb * 32 + lg * 8;
          bf16x8 ah[4], al[4];
          if (kb < 3) {
#pragma unroll
            for (int m = 0; m < 4; ++m) {
              ah[m] = *(const bf16x8*)(melh + ((size_t)t * B_ + 16 * m + lr) * 96 + k0);
              al[m] = *(const bf16x8*)(mell + ((size_t)t * B_ + 16 * m + lr) * 96 + k0);
            }
          } else {
            int k = k0 - 96;
#pragma unroll
            for (int m = 0; m < 4; ++m) {
              ah[m] = *(const bf16x8*)(ench + ((size_t)(16 * m + lr) * L_ + tq) * H_ + k);
              al[m] = *(const bf16x8*)(encl + ((size_t)(16 * m + lr) * L_ + tq) * H_ + k);
            }
          }
          MF(kb, ah, al);
        }
        // phase B: h0[t-1] frag-major IC loads, 1-deep prefetch
        {
          auto issue0 = [&](int kb, bf16x8 (&ah)[4], bf16x8 (&al)[4]) {
            const unsigned short* ph = p0h + ((size_t)((kb - 19) * 4) * 64 + ln) * 8;
            const unsigned short* pl = p0l + ((size_t)((kb - 19) * 4) * 64 + ln) * 8;
#pragma unroll
            for (int m = 0; m < 4; ++m) { ldc16(ah[m], ph + m * 512); ldc16(al[m], pl + m * 512); }
          };
          const int hkb0 = 19 + ((wv + 1) & 3);
          bf16x8 A0h[4], A0l[4], A1h[4], A1l[4];
          issue0(hkb0, A0h, A0l);
#pragma unroll
          for (int j = 0; j < 4; ++j) {
            const int kb = hkb0 + 4 * j;
            if (j & 1) {
              if (j < 3) issue0(kb + 4, A0h, A0l);
              VM_WAIT8_OR_0(j == 3);
              MF(kb, A1h, A1l);
            } else {
              if (j < 3) issue0(kb + 4, A1h, A1l);
              VM_WAIT8_OR_0(j == 3);
              MF(kb, A0h, A0l);
            }
          }
        }
      } else {
        const unsigned short* q0h = h0fh + (size_t)((tau + 1) & 1) * 32768;
        const unsigned short* q0l = h0fl + (size_t)((tau + 1) & 1) * 32768;
        const unsigned short* q1h = h1fh + (size_t)(tau & 1) * 32768;
        const unsigned short* q1l = h1fl + (size_t)(tau & 1) * 32768;
        auto issue1 = [&](int kb, bf16x8 (&ah)[4], bf16x8 (&al)[4]) {
          const unsigned short* ph = (kb < 16) ? (q0h + ((size_t)(kb * 4) * 64 + ln) * 8)
                                               : (q1h + ((size_t)((kb - 16) * 4) * 64 + ln) * 8);
          const unsigned short* pl = (kb < 16) ? (q0l + ((size_t)(kb * 4) * 64 + ln) * 8)
                                               : (q1l + ((size_t)((kb - 16) * 4) * 64 + ln) * 8);
#pragma unroll
          for (int m = 0; m < 4; ++m) { ldc16(ah[m], ph + m * 512); ldc16(al[m], pl + m * 512); }
        };
        bf16x8 A0h[4], A0l[4], A1h[4], A1l[4];
        issue1(wv, A0h, A0l);
#pragma unroll
        for (int i = 0; i < 8; ++i) {
          const int kb = wv + 4 * i;
          if (i & 1) {
            if (i < 7) issue1(kb + 4, A0h, A0l);
            VM_WAIT8_OR_0(i == 7);
            MF(kb, A1h, A1l);
          } else {
            if (i < 7) issue1(kb + 4, A1h, A1l);
            VM_WAIT8_OR_0(i == 7);
            MF(kb, A0h, A0l);
          }
        }
      }
      __syncthreads();
#pragma unroll
      for (int st = 0; st < 2; ++st)
#pragma unroll
        for (int m = 0; m < 4; ++m)
#pragma unroll
          for (int r = 0; r < 4; ++r) {
            int g = 2 * st + (lr >> 3), col = lr & 7;
            atomicAdd(&G[(g * 64 + 16 * m + 4 * lg + r) * 8 + col], acc[st][m][r]);
          }
      __syncthreads();

      {
        unsigned short* dh = layer ? (h1fh + (size_t)((tau + 1) & 1) * 32768)
                                   : (h0fh + (size_t)(tau & 1) * 32768);
        unsigned short* dl = layer ? (h1fl + (size_t)((tau + 1) & 1) * 32768)
                                   : (h0fl + (size_t)(tau & 1) * 32768);
        unsigned short hh[2], hl[2];
#pragma unroll
        for (int q = 0; q < 2; ++q) {
          int c = cc0 + q;
          float gi = G[(0 * 64 + ebd) * 8 + c];
          float gf = G[(1 * 64 + ebd) * 8 + c];
          float gg = G[(2 * 64 + ebd) * 8 + c];
          float go = G[(3 * 64 + ebd) * 8 + c];
          float cn = sigm(gf) * c2[q] + sigm(gi) * tanh_(gg);
          c2[q] = cn;
          float h = sigm(go) * tanh_(cn);
          split2(h, hh[q], hl[q]);
        }
        unsigned ph = (unsigned)hh[0] | ((unsigned)hh[1] << 16);
        unsigned pl = (unsigned)hl[0] | ((unsigned)hl[1] << 16);
        st4c(dh + frw, ph);
        st4c(dl + frw, pl);
        if (layer) *(unsigned*)(h2_full + ((size_t)t * B_ + ebd) * H_ + jcb + cc0) = ph;
      }
      VM_DRAIN();
    }
    grid_bar(bar, 128, tau);
  }
}

// ---------------------------------------------------------------------------
constexpr int MLP_LDS = 64 * 1024;

__global__ void __launch_bounds__(256) k_mlp(
    const unsigned short* __restrict__ h2_full,
    const unsigned short* __restrict__ w1_bf, const unsigned short* __restrict__ w2_bf,
    const float* __restrict__ mb1, const float* __restrict__ mb2,
    const float* __restrict__ stW, const float* __restrict__ stb, float* out) {
  extern __shared__ char lds[];
  const int t = blockIdx.x;
  const int tid = threadIdx.x, wv = tid >> 6, ln = tid & 63, lg = ln >> 4, lr = ln & 15;
  const unsigned short* A = h2_full + (size_t)t * B_ * H_;

  for (int half = 0; half < 2; ++half) {
    const int nb = wv * 8 + half * 4;
    f32x4 acc[4][4];
#pragma unroll
    for (int nn = 0; nn < 4; ++nn) {
      float bv = mb1[(nb + nn) * 16 + lr];
#pragma unroll
      for (int m = 0; m < 4; ++m) acc[m][nn] = (f32x4){bv, bv, bv, bv};
    }
    for (int kb = 0; kb < 16; ++kb) {
      int k0 = kb * 32 + lg * 8;
      bf16x8 afr[4], bfr[4];
#pragma unroll
      for (int m = 0; m < 4; ++m) afr[m] = *(const bf16x8*)(A + (size_t)(16 * m + lr) * H_ + k0);
#pragma unroll
      for (int nn = 0; nn < 4; ++nn) bfr[nn] = *(const bf16x8*)(w1_bf + (size_t)((nb + nn) * 16 + lr) * H_ + k0);
#pragma unroll
      for (int m = 0; m < 4; ++m)
#pragma unroll
        for (int nn = 0; nn < 4; ++nn) acc[m][nn] = mfma16(afr[m], bfr[nn], acc[m][nn]);
    }
#pragma unroll
    for (int m = 0; m < 4; ++m)
#pragma unroll
      for (int nn = 0; nn < 4; ++nn)
#pragma unroll
        for (int r = 0; r < 4; ++r) {
          int row = 16 * m + 4 * lg + r, col = (nb + nn) * 16 + lr;
          *(unsigned short*)(lds + row * 1024 + ((col * 2) ^ ((row & 7) << 4))) =
              f2bs(fmaxf(acc[m][nn][r], 0.f));
        }
  }
  __syncthreads();

  {
    f32x4 acc2[5];
#pragma unroll
    for (int n = 0; n < 5; ++n) {
      float bv = mb2[n * 16 + lr];
      acc2[n] = (f32x4){bv, bv, bv, bv};
    }
    for (int kb = 0; kb < 16; ++kb) {
      int k0 = kb * 32 + lg * 8;
      int row = 16 * wv + lr;
      bf16x8 afr = *(bf16x8*)(lds + row * 1024 + ((k0 * 2) ^ ((row & 7) << 4)));
#pragma unroll
      for (int n = 0; n < 5; ++n) {
        bf16x8 bfr = *(const bf16x8*)(w2_bf + (size_t)(n * 16 + lr) * H_ + k0);
        acc2[n] = mfma16(afr, bfr, acc2[n]);
      }
    }
#pragma unroll
    for (int n = 0; n < 5; ++n)
#pragma unroll
      for (int r = 0; r < 4; ++r) {
        int b = 16 * wv + 4 * lg + r;
        out[((size_t)b * T_ + t) * M_ + n * 16 + lr] = acc2[n][r];
      }
  }

  if (tid < 64) {
    int b = tid;
    float s = stb[0];
    const unsigned short* hp = A + (size_t)b * H_;
    for (int k = 0; k < H_; ++k) s += b2f(hp[k]) * stW[k];
    out[(size_t)B_ * T_ * M_ + (size_t)b * T_ + t] = s;
  }
}

// ---------------------------------------------------------------------------
extern "C" void kernel_launch(void* const* d_in, const int* in_sizes, int n_in,
                              void* d_out, int out_size, void* d_ws, size_t ws_size,
                              hipStream_t stream) {
  (void)in_sizes; (void)n_in; (void)out_size; (void)ws_size;
  const int* text = (const int*)d_in[0];
  const float* spk = (const float*)d_in[1];
  const float* tmel = (const float*)d_in[2];
  const float* embed = (const float*)d_in[3];
  const float* eWihF = (const float*)d_in[4];
  const float* eWhhF = (const float*)d_in[5];
  const float* ebF = (const float*)d_in[6];
  const float* eWihB = (const float*)d_in[7];
  const float* eWhhB = (const float*)d_in[8];
  const float* ebB = (const float*)d_in[9];
  const float* spW1 = (const float*)d_in[10];
  const float* spb1 = (const float*)d_in[11];
  const float* spW2 = (const float*)d_in[12];
  const float* spb2 = (const float*)d_in[13];
  const float* dWih0 = (const float*)d_in[14];
  const float* dWhh0 = (const float*)d_in[15];
  const float* db0 = (const float*)d_in[16];
  const float* dWih1 = (const float*)d_in[17];
  const float* dWhh1 = (const float*)d_in[18];
  const float* db1 = (const float*)d_in[19];
  const float* mW1 = (const float*)d_in[20];
  const float* mb1 = (const float*)d_in[21];
  const float* mW2 = (const float*)d_in[22];
  const float* mb2 = (const float*)d_in[23];
  const float* stW = (const float*)d_in[24];
  const float* stb = (const float*)d_in[25];
  float* out = (float*)d_out;

  char* base = (char*)d_ws;
  size_t off = 0;
  auto carve = [&](size_t bytes) -> void* {
    void* p = base + off;
    off += (bytes + 255) & ~(size_t)255;
    return p;
  };
  // --- state region (zeroed each call) ---
  Bar* barE = (Bar*)carve(sizeof(Bar));
  Bar* barD = (Bar*)carve(sizeof(Bar));
  unsigned short* h0fh = (unsigned short*)carve((size_t)2 * 32768 * 2);   // [par][16][4][64][8]
  unsigned short* h0fl = (unsigned short*)carve((size_t)2 * 32768 * 2);
  unsigned short* h1fh = (unsigned short*)carve((size_t)2 * 32768 * 2);
  unsigned short* h1fl = (unsigned short*)carve((size_t)2 * 32768 * 2);
  unsigned short* hencfh = (unsigned short*)carve((size_t)4 * 16384 * 2); // [par*2+dir][8][4][64][8]
  unsigned short* hencfl = (unsigned short*)carve((size_t)4 * 16384 * 2);
  const size_t state_bytes = off;
  // --- write-before-read buffers ---
  float* sp = (float*)carve((size_t)B_ * H_ * 4);
  unsigned short* emb_h = (unsigned short*)carve((size_t)256 * 256 * 2);
  unsigned short* emb_l = (unsigned short*)carve((size_t)256 * 256 * 2);
  unsigned short* mel_h = (unsigned short*)carve((size_t)T_ * B_ * 96 * 2);
  unsigned short* mel_l = (unsigned short*)carve((size_t)T_ * B_ * 96 * 2);
  unsigned short* w1_bf = (unsigned short*)carve((size_t)512 * 512 * 2);
  unsigned short* w2_bf = (unsigned short*)carve((size_t)80 * 512 * 2);
  unsigned short* ench = (unsigned short*)carve((size_t)B_ * L_ * H_ * 2);
  unsigned short* encl = (unsigned short*)carve((size_t)B_ * L_ * H_ * 2);
  unsigned short* h2_full = (unsigned short*)carve((size_t)T_ * B_ * H_ * 2);

  hipMemsetAsync(d_ws, 0, state_bytes, stream);

  hipFuncSetAttribute((const void*)k_enc, hipFuncAttributeMaxDynamicSharedMemorySize, ENC_LDS);
  hipFuncSetAttribute((const void*)k_dec, hipFuncAttributeMaxDynamicSharedMemorySize, DEC_LDS);
  hipFuncSetAttribute((const void*)k_mlp, hipFuncAttributeMaxDynamicSharedMemorySize, MLP_LDS);

  k_prep<<<2048, 256, 0, stream>>>(embed, tmel, mW1, mW2, emb_h, emb_l, mel_h, mel_l, w1_bf, w2_bf);
  k_sp<<<64, 512, 0, stream>>>(spk, spW1, spb1, spW2, spb2, sp);
  k_enc<<<32, 256, ENC_LDS, stream>>>(text, eWihF, eWhhF, ebF, eWihB, eWhhB, ebB,
                                      emb_h, emb_l, sp, hencfh, hencfl, ench, encl, barE);
  k_dec<<<128, 256, DEC_LDS, stream>>>(dWih0, dWhh0, db0, dWih1, dWhh1, db1,
                                       ench, encl, mel_h, mel_l,
                                       h0fh, h0fl, h1fh, h1fl, h2_full, barD);
  k_mlp<<<1000, 256, MLP_LDS, stream>>>(h2_full, w1_bf, w2_bf, mb1, mb2, stW, stb, out);
}